// Round 7
// baseline (179.158 us; speedup 1.0000x reference)
//
#include <hip/hip_runtime.h>

typedef __attribute__((ext_vector_type(8))) short bf16x8;
typedef __attribute__((ext_vector_type(4))) float f32x4;
typedef __attribute__((ext_vector_type(8))) unsigned short ushort8;

#define N_BLADES 32
#define B_DIM 1024
#define IN_DIM 256
#define OUT_DIM 256
#define K_DIM (IN_DIM * N_BLADES)   // 8192
#define N_DIM (OUT_DIM * N_BLADES)  // 8192

// ---------- helpers ----------

__device__ __forceinline__ unsigned short f2bf(float f) {
    unsigned int u = __float_as_uint(f);
    u = (u + 0x7fff + ((u >> 16) & 1)) >> 16;   // RNE
    return (unsigned short)u;
}

__device__ __forceinline__ float gp_sign(int a, int b) {
    int swaps = 0;
#pragma unroll
    for (int i = 0; i < 5; ++i) {
        int mask = (~((1 << (i + 1)) - 1)) & 31;
        swaps += ((b >> i) & 1) * __popc(a & mask);
    }
    float s = (swaps & 1) ? -1.0f : 1.0f;
    if (a & b & 16) s = -s;
    return s;
}

__device__ __forceinline__ void gload_lds16(const void* g, void* l) {
    __builtin_amdgcn_global_load_lds(
        (const __attribute__((address_space(1))) unsigned int*)g,
        (__attribute__((address_space(3))) unsigned int*)l, 16, 0, 0);
}

#define FENCE() asm volatile("" ::: "memory")
#define BAR()    { FENCE(); __builtin_amdgcn_s_barrier(); FENCE(); }
#define SCHED0() __builtin_amdgcn_sched_barrier(0)
#define LGKM(n)  { asm volatile("s_waitcnt lgkmcnt(" #n ")" ::: "memory"); SCHED0(); }
#define VMC(n)   { asm volatile("s_waitcnt vmcnt(" #n ")" ::: "memory"); SCHED0(); }
#define PRIO1()  __builtin_amdgcn_s_setprio(1)
#define PRIO0()  __builtin_amdgcn_s_setprio(0)

// ---------- prep: cast fp32 -> bf16 (8 elems/thread) ----------
__global__ __launch_bounds__(256) void cast_kernel(const float4* __restrict__ x,
                                                   unsigned short* __restrict__ xb) {
    int t = blockIdx.x * 256 + threadIdx.x;
    float4 a = x[t * 2];
    float4 b = x[t * 2 + 1];
    ushort8 pk;
    pk[0] = f2bf(a.x); pk[1] = f2bf(a.y); pk[2] = f2bf(a.z); pk[3] = f2bf(a.w);
    pk[4] = f2bf(b.x); pk[5] = f2bf(b.y); pk[6] = f2bf(b.z); pk[7] = f2bf(b.w);
    *(ushort8*)(xb + (size_t)t * 8) = pk;
}

// ---------- uniform-j XOR shuffle + sign mask on a bf16 octet ----------
// dest[e] = src[e^j] ^ signbit(msk, e)
__device__ __forceinline__ bf16x8 shuffle_sign(bf16x8 v, int jx,
                                               unsigned int m0, unsigned int m1,
                                               unsigned int m2, unsigned int m3) {
    union { bf16x8 v8; unsigned int w[4]; } a, b;
    a.v8 = v;
    int s = jx >> 1;
    unsigned int t0 = (s & 1) ? a.w[1] : a.w[0];
    unsigned int t1 = (s & 1) ? a.w[0] : a.w[1];
    unsigned int t2 = (s & 1) ? a.w[3] : a.w[2];
    unsigned int t3 = (s & 1) ? a.w[2] : a.w[3];
    unsigned int u0 = (s & 2) ? t2 : t0;
    unsigned int u1 = (s & 2) ? t3 : t1;
    unsigned int u2 = (s & 2) ? t0 : t2;
    unsigned int u3 = (s & 2) ? t1 : t3;
    if (jx & 1) {
        u0 = (u0 >> 16) | (u0 << 16);
        u1 = (u1 >> 16) | (u1 << 16);
        u2 = (u2 >> 16) | (u2 << 16);
        u3 = (u3 >> 16) | (u3 << 16);
    }
    b.w[0] = u0 ^ m0; b.w[1] = u1 ^ m1; b.w[2] = u2 ^ m2; b.w[3] = u3 ^ m3;
    return b.v8;
}

// ================= GEMM, N ordered (k,o): Cws[b][k*256+o] =================
// Block = one k x one o-half (128) x 128 b-rows. BM=128 BN=128 BK=64.
// 256 threads (4 waves 2Mx2N, wave tile 64x64). LDS = 2 x (A 16KB + B 16KB)
// = 64KB -> TWO blocks/CU co-resident: cross-block overlap fills barrier
// bubbles (the R6 structure had 144KB -> 1 block/CU, MfmaUtil 42%).
// B-operand = w_bf direct via global_load_lds (pre-swizzled source).
// A-operand = x[b][m^k]*sign(m,m^k): 4 octets/thread reg-staged with
// octet-XOR source addr + uniform-j register shuffle + sign-bit XOR mask,
// swizzled ds_write. One barrier/tile; strict counted vmcnt/lgkm ledger.

#define ROWB 16384    // bytes per K-row (8192 bf16)
#define BOFF 16384    // B offset within a buffer
#define BUFB 32768    // bytes per buffer

__global__ __launch_bounds__(256, 2) void gemm_ko2_kernel(const unsigned short* __restrict__ xb,
                                                          const unsigned short* __restrict__ wb,
                                                          float* __restrict__ Cws) {
    __shared__ char lds[2 * BUFB];

    const int tid  = threadIdx.x;
    const int lane = tid & 63;
    const int wid  = tid >> 6;          // 0..3
    const int wr   = wid >> 1;          // 0..1
    const int wc   = wid & 1;           // 0..1
    const int l15  = lane & 15;
    const int l4   = lane >> 4;
    const int swzf = (l15 & 7) << 4;

    const int  kblk = blockIdx.x;       // the k of this block
    const long col0 = (long)blockIdx.y * 128;   // o-half
    const long row0 = (long)blockIdx.z * 128;   // b-rows
    const int  jx   = kblk & 7;
    const int  khi  = kblk & 24;

    // ---- A reg-staging constants: thread owns row rA8 = tid>>1, slots hbase..hbase+3
    const int rA8   = tid >> 1;
    const int hbase = (tid & 1) * 4;
    const int isub  = (tid & 1);        // (hbase+n)>>2 == tid&1 for n<4
    const char* aSrcX = (const char*)xb + (row0 + rA8) * ROWB;
    const int aoff0 = isub * 64 + (((0 * 8) ^ khi) * 2);
    const int aoff1 = isub * 64 + (((1 * 8) ^ khi) * 2);
    const int aoff2 = isub * 64 + (((2 * 8) ^ khi) * 2);
    const int aoff3 = isub * 64 + (((3 * 8) ^ khi) * 2);
    const int aswz  = (rA8 & 7) << 4;
    const int adst0 = rA8 * 128 + (((hbase + 0) * 16) ^ aswz);
    const int adst1 = rA8 * 128 + (((hbase + 1) * 16) ^ aswz);
    const int adst2 = rA8 * 128 + (((hbase + 2) * 16) ^ aswz);
    const int adst3 = rA8 * 128 + (((hbase + 3) * 16) ^ aswz);

    // sign masks: mk[q][word], q = slot-octet (0..3), same for all threads
    unsigned int mk[4][4];
#pragma unroll
    for (int n = 0; n < 4; ++n)
#pragma unroll
        for (int w_ = 0; w_ < 4; ++w_) {
            unsigned int mw = 0;
#pragma unroll
            for (int e2 = 0; e2 < 2; ++e2) {
                int m = 8 * n + 2 * w_ + e2;
                if (gp_sign(m, m ^ kblk) < 0.0f) mw |= 0x8000u << (16 * e2);
            }
            mk[n][w_] = mw;
        }

    // ---- B staging constants (gload_lds, pre-swizzled source)
    const int  tid16 = tid * 16;
    const char* bSrcW = (const char*)wb + (col0 + (tid >> 3)) * ROWB
                        + (((tid & 7) * 16) ^ (((tid >> 3) & 7) << 4));

#define B_STAGE(nbuf, kpb) { \
    _Pragma("unroll") for (int n = 0; n < 4; ++n) \
        gload_lds16(bSrcW + (long)n * (32L * ROWB) + (kpb), (char*)(nbuf) + BOFF + n * 4096 + tid16); }
#define A_LOAD(kpb) { \
    rA0_ = *(const bf16x8*)(aSrcX + (kpb) + aoff0); \
    rA1_ = *(const bf16x8*)(aSrcX + (kpb) + aoff1); \
    rA2_ = *(const bf16x8*)(aSrcX + (kpb) + aoff2); \
    rA3_ = *(const bf16x8*)(aSrcX + (kpb) + aoff3); }
#define A_SHUF_WRITE(nbuf) { \
    bf16x8 s0_ = shuffle_sign(rA0_, jx, mk[0][0], mk[0][1], mk[0][2], mk[0][3]); \
    bf16x8 s1_ = shuffle_sign(rA1_, jx, mk[1][0], mk[1][1], mk[1][2], mk[1][3]); \
    bf16x8 s2_ = shuffle_sign(rA2_, jx, mk[2][0], mk[2][1], mk[2][2], mk[2][3]); \
    bf16x8 s3_ = shuffle_sign(rA3_, jx, mk[3][0], mk[3][1], mk[3][2], mk[3][3]); \
    *(bf16x8*)((char*)(nbuf) + adst0) = s0_; \
    *(bf16x8*)((char*)(nbuf) + adst1) = s1_; \
    *(bf16x8*)((char*)(nbuf) + adst2) = s2_; \
    *(bf16x8*)((char*)(nbuf) + adst3) = s3_; }
#define READ8(pbuf, kk) { \
    _Pragma("unroll") for (int mi = 0; mi < 4; ++mi) { \
        int r = wr * 64 + mi * 16 + l15; \
        aF[kk][mi] = *(const bf16x8*)((const char*)(pbuf) + r * 128 + (((kk) * 64 + l4 * 16) ^ swzf)); } \
    _Pragma("unroll") for (int ni = 0; ni < 4; ++ni) { \
        int r = wc * 64 + ni * 16 + l15; \
        bF[kk][ni] = *(const bf16x8*)((const char*)(pbuf) + BOFF + r * 128 + (((kk) * 64 + l4 * 16) ^ swzf)); } }
#define MFMA16(kk) \
    _Pragma("unroll") for (int mi = 0; mi < 4; ++mi) \
    _Pragma("unroll") for (int ni = 0; ni < 4; ++ni) \
        acc[mi][ni] = __builtin_amdgcn_mfma_f32_16x16x32_bf16(aF[kk][mi], bF[kk][ni], acc[mi][ni], 0, 0, 0);

    f32x4 acc[4][4];
#pragma unroll
    for (int mi = 0; mi < 4; ++mi)
#pragma unroll
        for (int ni = 0; ni < 4; ++ni) acc[mi][ni] = (f32x4)0.0f;

    bf16x8 rA0_, rA1_, rA2_, rA3_;
    bf16x8 aF[2][4], bF[2][4];

    char* buf0 = lds;
    char* buf1 = lds + BUFB;

    // ---- prologue: tile0 into buf0; A(1) into regs
    A_LOAD(0);
    VMC(0);
    A_SHUF_WRITE(buf0);
    SCHED0();
    B_STAGE(buf0, 0);
    SCHED0();
    A_LOAD(128);
    SCHED0();
    LGKM(0);    // A(0) ds_writes done
    VMC(4);     // B(0) done (oldest 4); A(1) regs in flight
    BAR();

    // steady state in-flight at tile entry: A(t+1) reg-loads (4)
    for (int t = 0; t < 128; ++t) {
        char* pc = (t & 1) ? buf1 : buf0;
        char* pn = (t & 1) ? buf0 : buf1;
        const int kpn = ((t + 1) & 127) * 128;   // byte K-offset of tile t+1
        const int kp2 = ((t + 2) & 127) * 128;   // tile t+2 (wraps harmlessly)

        READ8(pc, 0);
        SCHED0();
        B_STAGE(pn, kpn);        // 4 vm; in-flight: A(t+1) 4 oldest + B(t+1) 4
        SCHED0();
        READ8(pc, 1);
        LGKM(8);                 // kk0 frags ready (8 reads outstanding)
        PRIO1(); MFMA16(0); PRIO0();
        VMC(4);                  // A(t+1) regs ready (B(t+1) still in flight)
        A_SHUF_WRITE(pn);        // 4 ds_writes
        SCHED0();
        A_LOAD(kp2);             // 4 vm; in-flight: B(t+1) 4 oldest + A(t+2) 4
        SCHED0();
        LGKM(4);                 // kk1 frags ready (4 writes outstanding)
        PRIO1(); MFMA16(1); PRIO0();
        LGKM(0);                 // A(t+1) writes visible
        VMC(4);                  // B(t+1) complete; A(t+2) stays in flight
        BAR();
    }

    // epilogue: C/D layout col=lane&15, row=(lane>>4)*4+j
    const int cr = l4 * 4;
#pragma unroll
    for (int mi = 0; mi < 4; ++mi)
#pragma unroll
        for (int ni = 0; ni < 4; ++ni)
#pragma unroll
            for (int jj = 0; jj < 4; ++jj) {
                long r = row0 + wr * 64 + mi * 16 + cr + jj;
                long c = (long)kblk * 256 + col0 + wc * 64 + ni * 16 + l15;
                Cws[r * N_DIM + c] = acc[mi][ni][jj];
            }

#undef B_STAGE
#undef A_LOAD
#undef A_SHUF_WRITE
#undef READ8
#undef MFMA16
}

// ---------- transpose: out[b][o*32+k] = Cws[b][k*256+o] ----------
__global__ __launch_bounds__(256) void transpose_kernel(const float* __restrict__ Cws,
                                                        float* __restrict__ out) {
    __shared__ float t[32 * 260];
    const int tid = threadIdx.x;
    const long b  = blockIdx.x;
    const float4* src = (const float4*)(Cws + b * N_DIM);
    float4*       dst = (float4*)(out + b * N_DIM);
#pragma unroll
    for (int r = 0; r < 8; ++r) {
        int f = tid + r * 256;          // float4 index in row
        float4 v = src[f];
        int k  = f >> 6;
        int c4 = (f & 63) * 4;
        *(float4*)&t[k * 260 + c4] = v;
    }
    __syncthreads();
#pragma unroll
    for (int r = 0; r < 8; ++r) {
        int g  = tid + r * 256;         // out float4 index
        int o  = g >> 3;
        int k0 = (g & 7) * 4;
        float4 v;
        v.x = t[(k0 + 0) * 260 + o];
        v.y = t[(k0 + 1) * 260 + o];
        v.z = t[(k0 + 2) * 260 + o];
        v.w = t[(k0 + 3) * 260 + o];
        dst[g] = v;
    }
}

// ---------- fallback (ws tiny): direct fp32, correct but slow ----------
__global__ __launch_bounds__(256) void fallback_gp_kernel(const float* __restrict__ x,
                                                          const float* __restrict__ w,
                                                          float* __restrict__ out) {
    __shared__ float xs[IN_DIM * 32];
    __shared__ float tab[1024];
    int tid = threadIdx.x;
    for (int idx = tid; idx < 1024; idx += 256) {
        int m = idx >> 5, k = idx & 31;
        tab[idx] = gp_sign(m, m ^ k);
    }
    int b = blockIdx.x;
    const float4* xrow = (const float4*)(x + (long)b * K_DIM);
    float4* xs4 = (float4*)xs;
    for (int idx = tid; idx < 2048; idx += 256) xs4[idx] = xrow[idx];
    __syncthreads();

    int wid = tid >> 6, lane = tid & 63;
    int o = blockIdx.y * 8 + wid;
    int k = lane & 31, half = lane >> 5;
    float acc = 0.f;
    const float* wrow = w + (long)o * K_DIM + half * 4096;
    for (int i = 0; i < 128; ++i) {
        int ib = (half * 128 + i) * 32;
#pragma unroll
        for (int m = 0; m < 32; ++m) {
            acc += xs[ib + (m ^ k)] * tab[m * 32 + k] * wrow[i * 32 + m];
        }
    }
    acc += __shfl_down(acc, 32);
    if (half == 0) out[((long)b * OUT_DIM + o) * 32 + k] = acc;
}

// ---------- launch ----------
extern "C" void kernel_launch(void* const* d_in, const int* in_sizes, int n_in,
                              void* d_out, int out_size, void* d_ws, size_t ws_size,
                              hipStream_t stream) {
    const float* x = (const float*)d_in[0];
    const float* w = (const float*)d_in[1];
    float* out = (float*)d_out;

    const size_t xb_bytes  = (size_t)B_DIM * K_DIM * 2;          // 16 MiB
    const size_t wb_bytes  = (size_t)OUT_DIM * IN_DIM * 32 * 2;  // 4.2 MB
    const size_t cw_bytes  = (size_t)B_DIM * N_DIM * 4;          // 32 MiB
    const size_t need = xb_bytes + wb_bytes + cw_bytes;          // ~54 MB

    if (ws_size >= need) {
        unsigned short* xbp = (unsigned short*)d_ws;
        unsigned short* wbp = (unsigned short*)((char*)d_ws + xb_bytes);
        float*          cws = (float*)((char*)d_ws + xb_bytes + wb_bytes);

        cast_kernel<<<dim3(4096), dim3(256), 0, stream>>>((const float4*)x, xbp);
        cast_kernel<<<dim3(1024), dim3(256), 0, stream>>>((const float4*)w, wbp);
        gemm_ko2_kernel<<<dim3(32, 2, 8), dim3(256), 0, stream>>>(xbp, wbp, cws);
        transpose_kernel<<<dim3(B_DIM), dim3(256), 0, stream>>>(cws, out);
    } else {
        fallback_gp_kernel<<<dim3(B_DIM, OUT_DIM / 8), dim3(256), 0, stream>>>(x, w, out);
    }
}

// Round 8
// 176.911 us; speedup vs baseline: 1.0127x; 1.0127x over previous
//
#include <hip/hip_runtime.h>

typedef __attribute__((ext_vector_type(8))) short bf16x8;
typedef __attribute__((ext_vector_type(16))) float f32x16;
typedef __attribute__((ext_vector_type(8))) unsigned short ushort8;

#define N_BLADES 32
#define B_DIM 1024
#define IN_DIM 256
#define OUT_DIM 256
#define K_DIM (IN_DIM * N_BLADES)   // 8192
#define N_DIM (OUT_DIM * N_BLADES)  // 8192

// ---------- helpers ----------

__device__ __forceinline__ unsigned short f2bf(float f) {
    unsigned int u = __float_as_uint(f);
    u = (u + 0x7fff + ((u >> 16) & 1)) >> 16;   // RNE
    return (unsigned short)u;
}

__device__ __forceinline__ float gp_sign(int a, int b) {
    int swaps = 0;
#pragma unroll
    for (int i = 0; i < 5; ++i) {
        int mask = (~((1 << (i + 1)) - 1)) & 31;
        swaps += ((b >> i) & 1) * __popc(a & mask);
    }
    float s = (swaps & 1) ? -1.0f : 1.0f;
    if (a & b & 16) s = -s;
    return s;
}

__device__ __forceinline__ void gload_lds16(const void* g, void* l) {
    __builtin_amdgcn_global_load_lds(
        (const __attribute__((address_space(1))) unsigned int*)g,
        (__attribute__((address_space(3))) unsigned int*)l, 16, 0, 0);
}

#define FENCE() asm volatile("" ::: "memory")
#define BAR()    { FENCE(); __builtin_amdgcn_s_barrier(); FENCE(); }
#define SCHED0() __builtin_amdgcn_sched_barrier(0)
#define LGKM(n)  { asm volatile("s_waitcnt lgkmcnt(" #n ")" ::: "memory"); }
#define VMC(n)   { asm volatile("s_waitcnt vmcnt(" #n ")" ::: "memory"); }

// ---------- prep: cast fp32 -> bf16 (8 elems/thread) ----------
__global__ __launch_bounds__(256) void cast_kernel(const float4* __restrict__ x,
                                                   unsigned short* __restrict__ xb) {
    int t = blockIdx.x * 256 + threadIdx.x;
    float4 a = x[t * 2];
    float4 b = x[t * 2 + 1];
    ushort8 pk;
    pk[0] = f2bf(a.x); pk[1] = f2bf(a.y); pk[2] = f2bf(a.z); pk[3] = f2bf(a.w);
    pk[4] = f2bf(b.x); pk[5] = f2bf(b.y); pk[6] = f2bf(b.z); pk[7] = f2bf(b.w);
    *(ushort8*)(xb + (size_t)t * 8) = pk;
}

// ---------- uniform-j XOR shuffle + sign mask on a bf16 octet ----------
__device__ __forceinline__ bf16x8 shuffle_sign(bf16x8 v, int jx,
                                               unsigned int m0, unsigned int m1,
                                               unsigned int m2, unsigned int m3) {
    union { bf16x8 v8; unsigned int w[4]; } a, b;
    a.v8 = v;
    int s = jx >> 1;
    unsigned int t0 = (s & 1) ? a.w[1] : a.w[0];
    unsigned int t1 = (s & 1) ? a.w[0] : a.w[1];
    unsigned int t2 = (s & 1) ? a.w[3] : a.w[2];
    unsigned int t3 = (s & 1) ? a.w[2] : a.w[3];
    unsigned int u0 = (s & 2) ? t2 : t0;
    unsigned int u1 = (s & 2) ? t3 : t1;
    unsigned int u2 = (s & 2) ? t0 : t2;
    unsigned int u3 = (s & 2) ? t1 : t3;
    if (jx & 1) {
        u0 = (u0 >> 16) | (u0 << 16);
        u1 = (u1 >> 16) | (u1 << 16);
        u2 = (u2 >> 16) | (u2 << 16);
        u3 = (u3 >> 16) | (u3 << 16);
    }
    b.w[0] = u0 ^ m0; b.w[1] = u1 ^ m1; b.w[2] = u2 ^ m2; b.w[3] = u3 ^ m3;
    return b.v8;
}

// ================= GEMM, N ordered (k,o), 32x32x16 MFMA, deep rings =================
// Block = one k x 128 b-rows. BM=128 BN=256 BK=64, 8 waves (2Mx4N), wave 64x64.
// LDS: A ring2 x 16KB + B ring4 x 32KB = 160KB (1 block/CU).
// Deep-prefetch ledger (vm ops per tile: Ar 2 + Bg 4, in order):
//   pending at tile entry = {Ar(T+1) 2, Bg(T+2) 4};
//   body: VMC(10) -> Ar(T+1) ready (issued 1 tile ago);
//         VMC(6)  -> Bg(T+2) ready (issued 1 tile ago, read 2 tiles later).
//   No wait ever targets loads issued in the same tile (R6 defect fixed).
// 16 MFMA/tile/wave in 2 clusters of 8, counted LGKM(8)/(2). 1 barrier/tile.
// Unroll x4 -> all buffer offsets compile-time. No setprio (m190).

#define ROWB 16384    // bytes per K-row (8192 bf16)

__global__ __launch_bounds__(512, 1) void gemm_ko32_kernel(const unsigned short* __restrict__ xb,
                                                           const unsigned short* __restrict__ wb,
                                                           float* __restrict__ Cws) {
    __shared__ char lds[163840];   // A: 2x16KB @0; B: 4x32KB @32768

    const int tid  = threadIdx.x;
    const int lane = tid & 63;
    const int wid  = tid >> 6;          // 0..7
    const int wr   = wid >> 2;          // 0..1
    const int wc   = wid & 3;           // 0..3
    const int l31  = lane & 31;
    const int l5   = lane >> 5;
    const int swzf = (l31 & 7) << 4;

    const int  kblk = blockIdx.x;
    const long row0 = (long)blockIdx.y * 128;
    const int  jx   = kblk & 7;
    const int  khi  = kblk & 24;

    // ---- A reg-staging (R6-verified mapping): rowA = tid>>2, octets h0,h0+1
    const int rowA = tid >> 2;
    const int h0   = (2 * tid) & 7;
    const int q0 = h0 & 3, q1 = (h0 + 1) & 3;
    const int aoff0 = ((h0 >> 2) * 64) + (((q0 * 8) ^ khi) * 2);
    const int aoff1 = (((h0 + 1) >> 2) * 64) + (((q1 * 8) ^ khi) * 2);
    const int aswz  = (rowA & 7) << 4;
    const int adst0 = rowA * 128 + ((h0 * 16) ^ aswz);
    const int adst1 = rowA * 128 + (((h0 + 1) * 16) ^ aswz);
    const char* aSrcK = (const char*)xb + (row0 + rowA) * ROWB;

    unsigned int mA00, mA01, mA02, mA03, mA10, mA11, mA12, mA13;
    {
        unsigned int mk[2][4];
#pragma unroll
        for (int u = 0; u < 2; ++u) {
            int q = u ? q1 : q0;
#pragma unroll
            for (int w_ = 0; w_ < 4; ++w_) {
                unsigned int mw = 0;
#pragma unroll
                for (int e2 = 0; e2 < 2; ++e2) {
                    int m = 8 * q + 2 * w_ + e2;
                    if (gp_sign(m, m ^ kblk) < 0.0f) mw |= 0x8000u << (16 * e2);
                }
                mk[u][w_] = mw;
            }
        }
        mA00 = mk[0][0]; mA01 = mk[0][1]; mA02 = mk[0][2]; mA03 = mk[0][3];
        mA10 = mk[1][0]; mA11 = mk[1][1]; mA12 = mk[1][2]; mA13 = mk[1][3];
    }

    // ---- B staging constants (gload_lds, pre-swizzled source; R6-verified)
    const int  tid16 = tid * 16;
    const char* bSrc = (const char*)wb + (long)(tid >> 3) * ROWB
                       + (((tid & 7) * 16) ^ (((tid >> 3) & 7) << 4));

    // ---- fragment-read bases (32x32x16: row=lane&31, k=(lane>>5)*8+e)
    const int aRdB = (wr * 64 + l31) * 128;
    const int bRdB = (wc * 64 + l31) * 128;
    const int col0_ = ((0 * 32) + l5 * 16) ^ swzf;
    const int col1_ = ((1 * 32) + l5 * 16) ^ swzf;
    const int col2_ = ((2 * 32) + l5 * 16) ^ swzf;
    const int col3_ = ((3 * 32) + l5 * 16) ^ swzf;

#define B_STAGE(br, kpb) { \
    _Pragma("unroll") for (int n = 0; n < 4; ++n) \
        gload_lds16(bSrc + (long)n * (64L * ROWB) + (kpb), \
                    lds + 32768 + (br) * 32768 + n * 8192 + tid16); }
#define A_LOAD_E(kpb) { \
    rAe0 = *(const bf16x8*)(aSrcK + (kpb) + aoff0); \
    rAe1 = *(const bf16x8*)(aSrcK + (kpb) + aoff1); }
#define A_LOAD_O(kpb) { \
    rAo0 = *(const bf16x8*)(aSrcK + (kpb) + aoff0); \
    rAo1 = *(const bf16x8*)(aSrcK + (kpb) + aoff1); }
#define A_WRITE_E(ab) { \
    bf16x8 s0_ = shuffle_sign(rAe0, jx, mA00, mA01, mA02, mA03); \
    bf16x8 s1_ = shuffle_sign(rAe1, jx, mA10, mA11, mA12, mA13); \
    *(bf16x8*)(lds + (ab) * 16384 + adst0) = s0_; \
    *(bf16x8*)(lds + (ab) * 16384 + adst1) = s1_; }
#define A_WRITE_O(ab) { \
    bf16x8 s0_ = shuffle_sign(rAo0, jx, mA00, mA01, mA02, mA03); \
    bf16x8 s1_ = shuffle_sign(rAo1, jx, mA10, mA11, mA12, mA13); \
    *(bf16x8*)(lds + (ab) * 16384 + adst0) = s0_; \
    *(bf16x8*)(lds + (ab) * 16384 + adst1) = s1_; }

// G0: ks 0,1   G1: ks 2,3
#define READ_G0(ab, br) { \
    aG0[0][0] = *(const bf16x8*)(lds + (ab)*16384 + aRdB + 0*4096 + col0_); \
    aG0[0][1] = *(const bf16x8*)(lds + (ab)*16384 + aRdB + 0*4096 + col1_); \
    aG0[1][0] = *(const bf16x8*)(lds + (ab)*16384 + aRdB + 1*4096 + col0_); \
    aG0[1][1] = *(const bf16x8*)(lds + (ab)*16384 + aRdB + 1*4096 + col1_); \
    bG0[0][0] = *(const bf16x8*)(lds + 32768 + (br)*32768 + bRdB + 0*4096 + col0_); \
    bG0[0][1] = *(const bf16x8*)(lds + 32768 + (br)*32768 + bRdB + 0*4096 + col1_); \
    bG0[1][0] = *(const bf16x8*)(lds + 32768 + (br)*32768 + bRdB + 1*4096 + col0_); \
    bG0[1][1] = *(const bf16x8*)(lds + 32768 + (br)*32768 + bRdB + 1*4096 + col1_); }
#define READ_G1(ab, br) { \
    aG1[0][0] = *(const bf16x8*)(lds + (ab)*16384 + aRdB + 0*4096 + col2_); \
    aG1[0][1] = *(const bf16x8*)(lds + (ab)*16384 + aRdB + 0*4096 + col3_); \
    aG1[1][0] = *(const bf16x8*)(lds + (ab)*16384 + aRdB + 1*4096 + col2_); \
    aG1[1][1] = *(const bf16x8*)(lds + (ab)*16384 + aRdB + 1*4096 + col3_); \
    bG1[0][0] = *(const bf16x8*)(lds + 32768 + (br)*32768 + bRdB + 0*4096 + col2_); \
    bG1[0][1] = *(const bf16x8*)(lds + 32768 + (br)*32768 + bRdB + 0*4096 + col3_); \
    bG1[1][0] = *(const bf16x8*)(lds + 32768 + (br)*32768 + bRdB + 1*4096 + col2_); \
    bG1[1][1] = *(const bf16x8*)(lds + 32768 + (br)*32768 + bRdB + 1*4096 + col3_); }
#define MFG0() \
    _Pragma("unroll") for (int s = 0; s < 2; ++s) \
    _Pragma("unroll") for (int mt = 0; mt < 2; ++mt) \
    _Pragma("unroll") for (int nt = 0; nt < 2; ++nt) \
        acc[mt][nt] = __builtin_amdgcn_mfma_f32_32x32x16_bf16(aG0[mt][s], bG0[nt][s], acc[mt][nt], 0, 0, 0);
#define MFG1() \
    _Pragma("unroll") for (int s = 0; s < 2; ++s) \
    _Pragma("unroll") for (int mt = 0; mt < 2; ++mt) \
    _Pragma("unroll") for (int nt = 0; nt < 2; ++nt) \
        acc[mt][nt] = __builtin_amdgcn_mfma_f32_32x32x16_bf16(aG1[mt][s], bG1[nt][s], acc[mt][nt], 0, 0, 0);

    f32x16 acc[2][2];
#pragma unroll
    for (int mt = 0; mt < 2; ++mt)
#pragma unroll
        for (int nt = 0; nt < 2; ++nt) acc[mt][nt] = (f32x16)0.0f;

    bf16x8 rAe0, rAe1, rAo0, rAo1;
    bf16x8 aG0[2][2], bG0[2][2], aG1[2][2], bG1[2][2];

    // ---- prologue (ledger-exact): end pending = {Ar(1) 2, Bg(2) 4}
    A_LOAD_E(0);            // Ar(0) [2]
    SCHED0();
    B_STAGE(0, 0);          // Bg(0) [6]
    B_STAGE(1, 128);        // Bg(1) [10]
    SCHED0();
    VMC(8);                 // Ar(0) done
    A_WRITE_E(0);           // A(0) -> abuf0
    SCHED0();
    A_LOAD_O(128);          // Ar(1) [pending Bg0,Bg1,Ar1 = 10]
    SCHED0();
    B_STAGE(2, 256);        // Bg(2) [14]
    SCHED0();
    VMC(6);                 // retire Bg0,Bg1 -> pending {Ar1, Bg2} = 6
    LGKM(0);                // A(0) writes done
    BAR();

    // body: T = tile index; ab=T&1, br=T&3; A loads ping-pong with T parity
#define TILE32(AB, ABN, BR, BRS, ALOAD, AWRITE, Texp) { \
    const int T_ = (Texp); \
    const int kAr = ((T_ + 2) & 127) << 7; \
    const int kBg = ((T_ + 3) & 127) << 7; \
    READ_G0(AB, BR); \
    SCHED0(); \
    READ_G1(AB, BR); \
    SCHED0(); \
    ALOAD(kAr);            /* Ar(T+2), 2 vm */ \
    SCHED0(); \
    B_STAGE(BRS, kBg);     /* Bg(T+3), 4 vm */ \
    SCHED0(); \
    LGKM(8); MFG0(); \
    VMC(10);               /* Ar(T+1) ready (issued tile T-1) */ \
    AWRITE(ABN); \
    SCHED0(); \
    LGKM(2); MFG1(); \
    LGKM(0); \
    VMC(6);                /* Bg(T+2) ready (issued tile T-1) */ \
    BAR(); }

    for (int t = 0; t < 32; ++t) {
        const int T4 = t * 4;
        TILE32(0, 1, 0, 3, A_LOAD_E, A_WRITE_O, T4);
        TILE32(1, 0, 1, 0, A_LOAD_O, A_WRITE_E, T4 + 1);
        TILE32(0, 1, 2, 1, A_LOAD_E, A_WRITE_O, T4 + 2);
        TILE32(1, 0, 3, 2, A_LOAD_O, A_WRITE_E, T4 + 3);
    }

    // ---- epilogue: 32x32 C/D layout col=lane&31, row=(r&3)+8*(r>>2)+4*l5 (m74/m101)
#pragma unroll
    for (int mt = 0; mt < 2; ++mt)
#pragma unroll
        for (int nt = 0; nt < 2; ++nt) {
            long c = (long)kblk * 256 + wc * 64 + nt * 32 + l31;
#pragma unroll
            for (int r = 0; r < 16; ++r) {
                int  rl = (r & 3) + 8 * (r >> 2) + 4 * l5;
                long rb = row0 + wr * 64 + mt * 32 + rl;
                Cws[rb * N_DIM + c] = acc[mt][nt][r];
            }
        }

#undef B_STAGE
#undef A_LOAD_E
#undef A_LOAD_O
#undef A_WRITE_E
#undef A_WRITE_O
#undef READ_G0
#undef READ_G1
#undef MFG0
#undef MFG1
#undef TILE32
}

// ---------- transpose: out[b][o*32+k] = Cws[b][k*256+o] ----------
__global__ __launch_bounds__(256) void transpose_kernel(const float* __restrict__ Cws,
                                                        float* __restrict__ out) {
    __shared__ float t[32 * 260];
    const int tid = threadIdx.x;
    const long b  = blockIdx.x;
    const float4* src = (const float4*)(Cws + b * N_DIM);
    float4*       dst = (float4*)(out + b * N_DIM);
#pragma unroll
    for (int r = 0; r < 8; ++r) {
        int f = tid + r * 256;
        float4 v = src[f];
        int k  = f >> 6;
        int c4 = (f & 63) * 4;
        *(float4*)&t[k * 260 + c4] = v;
    }
    __syncthreads();
#pragma unroll
    for (int r = 0; r < 8; ++r) {
        int g  = tid + r * 256;
        int o  = g >> 3;
        int k0 = (g & 7) * 4;
        float4 v;
        v.x = t[(k0 + 0) * 260 + o];
        v.y = t[(k0 + 1) * 260 + o];
        v.z = t[(k0 + 2) * 260 + o];
        v.w = t[(k0 + 3) * 260 + o];
        dst[g] = v;
    }
}

// ---------- fallback (ws tiny): direct fp32, correct but slow ----------
__global__ __launch_bounds__(256) void fallback_gp_kernel(const float* __restrict__ x,
                                                          const float* __restrict__ w,
                                                          float* __restrict__ out) {
    __shared__ float xs[IN_DIM * 32];
    __shared__ float tab[1024];
    int tid = threadIdx.x;
    for (int idx = tid; idx < 1024; idx += 256) {
        int m = idx >> 5, k = idx & 31;
        tab[idx] = gp_sign(m, m ^ k);
    }
    int b = blockIdx.x;
    const float4* xrow = (const float4*)(x + (long)b * K_DIM);
    float4* xs4 = (float4*)xs;
    for (int idx = tid; idx < 2048; idx += 256) xs4[idx] = xrow[idx];
    __syncthreads();

    int wid = tid >> 6, lane = tid & 63;
    int o = blockIdx.y * 8 + wid;
    int k = lane & 31, half = lane >> 5;
    float acc = 0.f;
    const float* wrow = w + (long)o * K_DIM + half * 4096;
    for (int i = 0; i < 128; ++i) {
        int ib = (half * 128 + i) * 32;
#pragma unroll
        for (int m = 0; m < 32; ++m) {
            acc += xs[ib + (m ^ k)] * tab[m * 32 + k] * wrow[i * 32 + m];
        }
    }
    acc += __shfl_down(acc, 32);
    if (half == 0) out[((long)b * OUT_DIM + o) * 32 + k] = acc;
}

// ---------- launch ----------
extern "C" void kernel_launch(void* const* d_in, const int* in_sizes, int n_in,
                              void* d_out, int out_size, void* d_ws, size_t ws_size,
                              hipStream_t stream) {
    const float* x = (const float*)d_in[0];
    const float* w = (const float*)d_in[1];
    float* out = (float*)d_out;

    const size_t xb_bytes  = (size_t)B_DIM * K_DIM * 2;          // 16 MiB
    const size_t wb_bytes  = (size_t)OUT_DIM * IN_DIM * 32 * 2;  // 4.2 MB
    const size_t cw_bytes  = (size_t)B_DIM * N_DIM * 4;          // 32 MiB
    const size_t need = xb_bytes + wb_bytes + cw_bytes;          // ~54 MB

    if (ws_size >= need) {
        unsigned short* xbp = (unsigned short*)d_ws;
        unsigned short* wbp = (unsigned short*)((char*)d_ws + xb_bytes);
        float*          cws = (float*)((char*)d_ws + xb_bytes + wb_bytes);

        cast_kernel<<<dim3(4096), dim3(256), 0, stream>>>((const float4*)x, xbp);
        cast_kernel<<<dim3(1024), dim3(256), 0, stream>>>((const float4*)w, wbp);
        gemm_ko32_kernel<<<dim3(32, 8), dim3(512), 0, stream>>>(xbp, wbp, cws);
        transpose_kernel<<<dim3(B_DIM), dim3(256), 0, stream>>>(cws, out);
    } else {
        fallback_gp_kernel<<<dim3(B_DIM, OUT_DIM / 8), dim3(256), 0, stream>>>(x, w, out);
    }
}